// Round 3
// baseline (382.442 us; speedup 1.0000x reference)
//
#include <hip/hip_runtime.h>
#include <hip/hip_bf16.h>

typedef __attribute__((ext_vector_type(8))) short bf16x8;
typedef __attribute__((ext_vector_type(4))) float f32x4;
typedef unsigned short u16;

#define B_  2
#define T_  2048
#define C_  1024
#define H_  16
#define HD_ 64
#define CH  8    // kt tiles per attention chunk block

static __device__ __forceinline__ u16 f2bf(float f) {
  unsigned u = __float_as_uint(f);
  u += 0x7fffu + ((u >> 16) & 1u);   // round-to-nearest-even
  return (u16)(u >> 16);
}

// ---------------------------------------------------------------------------
// Kernel 0: convert X (4.19M) and W (2.10M) fp32 -> bf16, float4-vectorized.
// ---------------------------------------------------------------------------
#define NX4 1048576   // X float4 count
#define NW4 524288    // W float4 count
__global__ __launch_bounds__(256) void convert_bf16(
    const float* __restrict__ X, const float* __restrict__ W,
    u16* __restrict__ Xb, u16* __restrict__ Wb)
{
  int i = blockIdx.x * 256 + threadIdx.x;
  if (i < NX4) {
    float4 v = ((const float4*)X)[i];
    ushort4 u = { f2bf(v.x), f2bf(v.y), f2bf(v.z), f2bf(v.w) };
    ((ushort4*)Xb)[i] = u;
  } else {
    int j = i - NX4;
    float4 v = ((const float4*)W)[j];
    ushort4 u = { f2bf(v.x), f2bf(v.y), f2bf(v.z), f2bf(v.w) };
    ((ushort4*)Wb)[j] = u;
  }
}

// ---------------------------------------------------------------------------
// Kernel 1: qk = Xb @ Wb^T  (M=4096,N=2048,K=1024) m97-style:
// 128x128 tile, BK=64, global_load_lds width=16, 4 waves each 64x64.
// Epilogue scatters bf16 into Q/K laid out [B,H,T,hd].
// ---------------------------------------------------------------------------
__global__ __launch_bounds__(256) void gemm_qk(
    const u16* __restrict__ Xb, const u16* __restrict__ Wb,
    u16* __restrict__ Qo, u16* __restrict__ Ko)
{
  __shared__ __align__(16) u16 As[128 * 64];
  __shared__ __align__(16) u16 Bs[128 * 64];

  const int tid  = threadIdx.x;
  const int w    = tid >> 6;
  const int lane = tid & 63;
  const int quad = lane >> 4;
  const int l16  = lane & 15;
  const int m0 = blockIdx.y * 128;
  const int n0 = blockIdx.x * 128;

  const int grow = w * 8 + ((lane >> 3) & 7);
  const int gcol = (lane & 7) * 8;

  f32x4 zero = {0.f, 0.f, 0.f, 0.f};
  f32x4 acc[4][4];
#pragma unroll
  for (int i = 0; i < 4; ++i)
#pragma unroll
    for (int j = 0; j < 4; ++j) acc[i][j] = zero;

  const int wr = (w >> 1) * 64, wc = (w & 1) * 64;

  for (int k0 = 0; k0 < C_; k0 += 64) {
#pragma unroll
    for (int r = 0; r < 4; ++r) {
      const u16* ga = Xb + (size_t)(m0 + grow + r * 32) * C_ + k0 + gcol;
      const u16* gb = Wb + (size_t)(n0 + grow + r * 32) * C_ + k0 + gcol;
      __builtin_amdgcn_global_load_lds(
          (const __attribute__((address_space(1))) void*)ga,
          (__attribute__((address_space(3))) void*)&As[(w * 8 + r * 32) * 64],
          16, 0, 0);
      __builtin_amdgcn_global_load_lds(
          (const __attribute__((address_space(1))) void*)gb,
          (__attribute__((address_space(3))) void*)&Bs[(w * 8 + r * 32) * 64],
          16, 0, 0);
    }
    __syncthreads();
#pragma unroll
    for (int c = 0; c < 2; ++c) {
      bf16x8 af[4], bf[4];
#pragma unroll
      for (int i = 0; i < 4; ++i)
        af[i] = *(const bf16x8*)&As[(wr + i * 16 + l16) * 64 + c * 32 + quad * 8];
#pragma unroll
      for (int j = 0; j < 4; ++j)
        bf[j] = *(const bf16x8*)&Bs[(wc + j * 16 + l16) * 64 + c * 32 + quad * 8];
#pragma unroll
      for (int i = 0; i < 4; ++i)
#pragma unroll
        for (int j = 0; j < 4; ++j)
          acc[i][j] = __builtin_amdgcn_mfma_f32_16x16x32_bf16(af[i], bf[j], acc[i][j], 0, 0, 0);
    }
    __syncthreads();
  }

#pragma unroll
  for (int i = 0; i < 4; ++i) {
#pragma unroll
    for (int j = 0; j < 4; ++j) {
      int n = n0 + wc + j * 16 + l16;
      u16* dst = (n < C_) ? Qo : Ko;
      int nh = n & (C_ - 1);
      int h = nh >> 6, d = nh & 63;
#pragma unroll
      for (int r = 0; r < 4; ++r) {
        int m = m0 + wr + i * 16 + quad * 4 + r;
        int b = m >> 11, t = m & (T_ - 1);
        dst[(((size_t)b * H_ + h) * T_ + t) * HD_ + d] = f2bf(acc[i][j][r]);
      }
    }
  }
}

// ---------------------------------------------------------------------------
// Kernel 2: Vt[bh][d][t] = bf16(x[b][t][h*64+d])  (transposed via LDS tiles)
// ---------------------------------------------------------------------------
__global__ __launch_bounds__(256) void pack_vt(
    const float* __restrict__ X, u16* __restrict__ Vt)
{
  __shared__ __align__(16) u16 tr[64][72];
  const int bh = blockIdx.x, tc = blockIdx.y;
  const int b = bh >> 4, h = bh & 15;
  const int tid = threadIdx.x;
  {
    const int row = tid >> 2;
    const int c0  = (tid & 3) * 16;
    const float* xp = X + ((size_t)b * T_ + tc * 64 + row) * C_ + h * 64 + c0;
#pragma unroll
    for (int q = 0; q < 4; ++q) {
      float4 v = *(const float4*)(xp + q * 4);
      tr[c0 + q * 4 + 0][row] = f2bf(v.x);
      tr[c0 + q * 4 + 1][row] = f2bf(v.y);
      tr[c0 + q * 4 + 2][row] = f2bf(v.z);
      tr[c0 + q * 4 + 3][row] = f2bf(v.w);
    }
  }
  __syncthreads();
  {
    const int d  = tid >> 2;
    const int t0 = (tid & 3) * 16;
    u16* op = Vt + ((size_t)bh * HD_ + d) * T_ + tc * 64 + t0;
    *(bf16x8*)op       = *(const bf16x8*)&tr[d][t0];
    *(bf16x8*)(op + 8) = *(const bf16x8*)&tr[d][t0 + 8];
  }
}

// ---------------------------------------------------------------------------
// Kernel 3a/3b: two-pass prefix scan (512 blocks per pass).
// SubP[bh][gs][d] = sum of 32-row subchunk gs; then scanB adds prefix bases
// and writes SP[bh][t][d] = sum_{s<=t} x[b,s,h*64+d].
// ---------------------------------------------------------------------------
__global__ __launch_bounds__(256) void scanA(
    const float* __restrict__ X, float* __restrict__ SubP)
{
  const int ch = blockIdx.x, bh = blockIdx.y;
  const int b = bh >> 4, h = bh & 15;
  const int d = threadIdx.x & 63, s = threadIdx.x >> 6;
  const float* xp = X + (size_t)b * T_ * C_ + h * 64 + d;
  int t0 = ch * 128 + s * 32;
  float sum = 0.f;
#pragma unroll 8
  for (int i = 0; i < 32; ++i) sum += xp[(size_t)(t0 + i) * C_];
  SubP[((size_t)bh * 64 + ch * 4 + s) * 64 + d] = sum;
}

__global__ __launch_bounds__(256) void scanB(
    const float* __restrict__ X, const float* __restrict__ SubP,
    float* __restrict__ SP)
{
  const int ch = blockIdx.x, bh = blockIdx.y;
  const int b = bh >> 4, h = bh & 15;
  const int d = threadIdx.x & 63, s = threadIdx.x >> 6;
  const int gs = ch * 4 + s;                 // wave-uniform
  const float* pp = SubP + (size_t)bh * 64 * 64 + d;
  float base = 0.f;
  for (int i = 0; i < gs; ++i) base += pp[(size_t)i * 64];
  const float* xp = X + (size_t)b * T_ * C_ + h * 64 + d;
  float* op = SP + (size_t)bh * T_ * HD_ + d;
  float sum = base;
  int t0 = gs * 32;
#pragma unroll 4
  for (int i = 0; i < 32; ++i) {
    int t = t0 + i;
    sum += xp[(size_t)t * C_];
    op[(size_t)t * HD_] = sum;
  }
}

// ---------------------------------------------------------------------------
// Kernel 4: split-K flash attention chunk. Block = (chunk c, qt, bh):
// 64 q-rows x key tiles [c*8, min(qt+1, c*8+8)). No running max (scores
// bounded ~2.5); partial Sexp and P@V are associative -> accumulate with
// native fp32 atomics into ACC/LS. No __syncthreads anywhere.
// ---------------------------------------------------------------------------
__global__ __launch_bounds__(256) void attn_chunked(
    const u16* __restrict__ Q, const u16* __restrict__ K, const u16* __restrict__ Vt,
    float* __restrict__ ACC, float* __restrict__ LS)
{
  __shared__ __align__(16) u16 pbuf[4][16][72];

  const int c  = blockIdx.x;
  const int qt = 31 - blockIdx.y;           // LPT: big qt first
  const int bh = blockIdx.z;
  const int kt0 = c * CH;
  if (kt0 > qt) return;
  const int kt1 = (qt + 1 < kt0 + CH) ? (qt + 1) : (kt0 + CH);

  const int tid  = threadIdx.x;
  const int w    = tid >> 6;
  const int lane = tid & 63;
  const int quad = lane >> 4;
  const int l16  = lane & 15;

  const u16* qb  = Q  + (size_t)bh * T_ * HD_;
  const u16* kb  = K  + (size_t)bh * T_ * HD_;
  const u16* vtb = Vt + (size_t)bh * HD_ * T_;

  bf16x8 qfrag[2];
  {
    const u16* qp = qb + (size_t)(qt * 64 + w * 16 + l16) * HD_ + quad * 8;
    qfrag[0] = *(const bf16x8*)qp;
    qfrag[1] = *(const bf16x8*)(qp + 32);
  }

  f32x4 zero = {0.f, 0.f, 0.f, 0.f};
  f32x4 acc[4] = {zero, zero, zero, zero};
  float lsum[4] = {0.f, 0.f, 0.f, 0.f};
  const int myrow = w * 16 + quad * 4;

  for (int kt = kt0; kt < kt1; ++kt) {
    bf16x8 kf[2][4];
#pragma unroll
    for (int cc = 0; cc < 2; ++cc)
#pragma unroll
      for (int nb = 0; nb < 4; ++nb)
        kf[cc][nb] = *(const bf16x8*)&kb[(size_t)(kt * 64 + nb * 16 + l16) * HD_ + cc * 32 + quad * 8];
    bf16x8 vf[2][4];
#pragma unroll
    for (int cc = 0; cc < 2; ++cc)
#pragma unroll
      for (int nb = 0; nb < 4; ++nb)
        vf[cc][nb] = *(const bf16x8*)&vtb[(size_t)(nb * 16 + l16) * T_ + kt * 64 + cc * 32 + quad * 8];

    f32x4 sfr[4] = {zero, zero, zero, zero};
#pragma unroll
    for (int cc = 0; cc < 2; ++cc)
#pragma unroll
      for (int nb = 0; nb < 4; ++nb)
        sfr[nb] = __builtin_amdgcn_mfma_f32_16x16x32_bf16(qfrag[cc], kf[cc][nb], sfr[nb], 0, 0, 0);

    const bool diag = (kt == qt);
#pragma unroll
    for (int nb = 0; nb < 4; ++nb) {
#pragma unroll
      for (int r = 0; r < 4; ++r) {
        float p = __expf(sfr[nb][r] * 0.125f);
        if (diag && (nb * 16 + l16 > myrow + r)) p = 0.f;
        lsum[r] += p;
        pbuf[w][quad * 4 + r][nb * 16 + l16] = (u16)(__float_as_uint(p) >> 16);
      }
    }

#pragma unroll
    for (int cc = 0; cc < 2; ++cc) {
      bf16x8 pf = *(const bf16x8*)&pbuf[w][l16][cc * 32 + quad * 8];
#pragma unroll
      for (int nb = 0; nb < 4; ++nb)
        acc[nb] = __builtin_amdgcn_mfma_f32_16x16x32_bf16(pf, vf[cc][nb], acc[nb], 0, 0, 0);
    }
  }

  // partial row sums -> LS (one lane per row)
#pragma unroll
  for (int r = 0; r < 4; ++r) {
    float s = lsum[r];
    s += __shfl_xor(s, 1);
    s += __shfl_xor(s, 2);
    s += __shfl_xor(s, 4);
    s += __shfl_xor(s, 8);
    if (l16 == 0) unsafeAtomicAdd(&LS[(size_t)bh * T_ + qt * 64 + myrow + r], s);
  }
  // partial O -> ACC (coalesced fp32 atomics)
#pragma unroll
  for (int nb = 0; nb < 4; ++nb)
#pragma unroll
    for (int r = 0; r < 4; ++r) {
      int t = qt * 64 + myrow + r;
      unsafeAtomicAdd(&ACC[((size_t)bh * T_ + t) * HD_ + nb * 16 + l16], acc[nb][r]);
    }
}

// ---------------------------------------------------------------------------
// Kernel 5: finalize. out = beta*ACC/LS + alpha*x - gamma*SP/(t+1).
// ---------------------------------------------------------------------------
__global__ __launch_bounds__(256) void finalize(
    const float* __restrict__ ACC, const float* __restrict__ LS,
    const float* __restrict__ SP, const float* __restrict__ X,
    float* __restrict__ out,
    const float* __restrict__ alphap, const float* __restrict__ betap,
    const float* __restrict__ gammap)
{
  int idx = blockIdx.x * 256 + threadIdx.x;   // [bh][t][d4]
  int d4 = idx & 15;
  int t  = (idx >> 4) & (T_ - 1);
  int bh = idx >> 15;
  int b = bh >> 4, h = bh & 15;
  float4 a4 = ((const float4*)ACC)[idx];
  float4 s4 = ((const float4*)SP)[idx];
  float ls = LS[(size_t)bh * T_ + t];
  size_t xi = ((size_t)(b * T_ + t)) * C_ + h * 64 + d4 * 4;
  float4 x4 = *(const float4*)(X + xi);
  float alpha = *alphap, beta = *betap, gamma = *gammap;
  float bs = beta / ls;
  float gs = gamma / (float)(t + 1);
  float4 o;
  o.x = a4.x * bs + alpha * x4.x - gs * s4.x;
  o.y = a4.y * bs + alpha * x4.y - gs * s4.y;
  o.z = a4.z * bs + alpha * x4.z - gs * s4.z;
  o.w = a4.w * bs + alpha * x4.w - gs * s4.w;
  *(float4*)(out + xi) = o;
}

// ---------------------------------------------------------------------------
extern "C" void kernel_launch(void* const* d_in, const int* in_sizes, int n_in,
                              void* d_out, int out_size, void* d_ws, size_t ws_size,
                              hipStream_t stream) {
  const float* x      = (const float*)d_in[0];
  const float* W_attn = (const float*)d_in[1];
  const float* alphap = (const float*)d_in[2];
  const float* betap  = (const float*)d_in[3];
  const float* gammap = (const float*)d_in[4];
  float* out = (float*)d_out;

  // ws layout (ACC aliases Xb/Wb, which die after gemm_qk):
  // Qb@0(8M) Kb@8(8M) Vtb@16(8M) SPb@24(16M) SubP@40(.5M)
  // Xb@41(8M) Wb@49(4M) | ACC@41(16M) LS@57(.25M)   -> total 57.25 MB
  char* ws = (char*)d_ws;
  u16*   Qb   = (u16*)(ws);
  u16*   Kb   = (u16*)(ws + (8ull  << 20));
  u16*   Vtb  = (u16*)(ws + (16ull << 20));
  float* SPb  = (float*)(ws + (24ull << 20));
  float* SubP = (float*)(ws + (40ull << 20));
  u16*   Xb   = (u16*)(ws + (41ull << 20));
  u16*   Wb   = (u16*)(ws + (49ull << 20));
  float* ACC  = (float*)(ws + (41ull << 20));
  float* LS   = (float*)(ws + (57ull << 20));

  convert_bf16<<<(NX4 + NW4) / 256, 256, 0, stream>>>(x, W_attn, Xb, Wb);
  gemm_qk<<<dim3(16, 32), 256, 0, stream>>>(Xb, Wb, Qb, Kb);
  pack_vt<<<dim3(32, 32), 256, 0, stream>>>(x, Vtb);
  scanA<<<dim3(16, 32), 256, 0, stream>>>(x, SubP);
  scanB<<<dim3(16, 32), 256, 0, stream>>>(x, SubP, SPb);
  hipMemsetAsync(ws + (41ull << 20), 0, (16ull << 20) + (256ull << 10), stream);
  attn_chunked<<<dim3(4, 32, 32), 256, 0, stream>>>(Qb, Kb, Vtb, ACC, LS);
  finalize<<<4096, 256, 0, stream>>>(ACC, LS, SPb, x, out, alphap, betap, gammap);
}

// Round 4
// 183.572 us; speedup vs baseline: 2.0833x; 2.0833x over previous
//
#include <hip/hip_runtime.h>
#include <hip/hip_bf16.h>

typedef __attribute__((ext_vector_type(8))) short bf16x8;
typedef __attribute__((ext_vector_type(4))) float f32x4;
typedef unsigned short u16;

#define B_  2
#define T_  2048
#define C_  1024
#define H_  16
#define HD_ 64

static __device__ __forceinline__ u16 f2bf(float f) {
  unsigned u = __float_as_uint(f);
  u += 0x7fffu + ((u >> 16) & 1u);   // round-to-nearest-even
  return (u16)(u >> 16);
}

// ---------------------------------------------------------------------------
// Kernel 0: convert X (4.19M) and W (2.10M) fp32 -> bf16, float4-vectorized.
// ---------------------------------------------------------------------------
#define NX4 1048576   // X float4 count
#define NW4 524288    // W float4 count
__global__ __launch_bounds__(256) void convert_bf16(
    const float* __restrict__ X, const float* __restrict__ W,
    u16* __restrict__ Xb, u16* __restrict__ Wb)
{
  int i = blockIdx.x * 256 + threadIdx.x;
  if (i < NX4) {
    float4 v = ((const float4*)X)[i];
    ushort4 u = { f2bf(v.x), f2bf(v.y), f2bf(v.z), f2bf(v.w) };
    ((ushort4*)Xb)[i] = u;
  } else {
    int j = i - NX4;
    float4 v = ((const float4*)W)[j];
    ushort4 u = { f2bf(v.x), f2bf(v.y), f2bf(v.z), f2bf(v.w) };
    ((ushort4*)Wb)[j] = u;
  }
}

// ---------------------------------------------------------------------------
// Kernel 1: qk = Xb @ Wb^T  (M=4096,N=2048,K=1024), 128x128 tile, BK=64,
// global_load_lds width=16. Q written row-major [B,H,T,hd]; K written
// DIRECTLY into MFMA-B-fragment-linear layout Kf:
//   chunk (bh,kt,nb,c) is 1KB; lane (quad*16+l16) holds 16B =
//   K[key=kt*64+nb*16+l16][d = c*32+quad*8 .. +8]   -> attn loads coalesce.
// ---------------------------------------------------------------------------
__global__ __launch_bounds__(256) void gemm_qk(
    const u16* __restrict__ Xb, const u16* __restrict__ Wb,
    u16* __restrict__ Qo, u16* __restrict__ Kf)
{
  __shared__ __align__(16) u16 As[128 * 64];
  __shared__ __align__(16) u16 Bs[128 * 64];

  const int tid  = threadIdx.x;
  const int w    = tid >> 6;
  const int lane = tid & 63;
  const int quad = lane >> 4;
  const int l16  = lane & 15;
  const int m0 = blockIdx.y * 128;
  const int n0 = blockIdx.x * 128;

  const int grow = w * 8 + ((lane >> 3) & 7);
  const int gcol = (lane & 7) * 8;

  f32x4 zero = {0.f, 0.f, 0.f, 0.f};
  f32x4 acc[4][4];
#pragma unroll
  for (int i = 0; i < 4; ++i)
#pragma unroll
    for (int j = 0; j < 4; ++j) acc[i][j] = zero;

  const int wr = (w >> 1) * 64, wc = (w & 1) * 64;

  for (int k0 = 0; k0 < C_; k0 += 64) {
#pragma unroll
    for (int r = 0; r < 4; ++r) {
      const u16* ga = Xb + (size_t)(m0 + grow + r * 32) * C_ + k0 + gcol;
      const u16* gb = Wb + (size_t)(n0 + grow + r * 32) * C_ + k0 + gcol;
      __builtin_amdgcn_global_load_lds(
          (const __attribute__((address_space(1))) void*)ga,
          (__attribute__((address_space(3))) void*)&As[(w * 8 + r * 32) * 64],
          16, 0, 0);
      __builtin_amdgcn_global_load_lds(
          (const __attribute__((address_space(1))) void*)gb,
          (__attribute__((address_space(3))) void*)&Bs[(w * 8 + r * 32) * 64],
          16, 0, 0);
    }
    __syncthreads();
#pragma unroll
    for (int c = 0; c < 2; ++c) {
      bf16x8 af[4], bf[4];
#pragma unroll
      for (int i = 0; i < 4; ++i)
        af[i] = *(const bf16x8*)&As[(wr + i * 16 + l16) * 64 + c * 32 + quad * 8];
#pragma unroll
      for (int j = 0; j < 4; ++j)
        bf[j] = *(const bf16x8*)&Bs[(wc + j * 16 + l16) * 64 + c * 32 + quad * 8];
#pragma unroll
      for (int i = 0; i < 4; ++i)
#pragma unroll
        for (int j = 0; j < 4; ++j)
          acc[i][j] = __builtin_amdgcn_mfma_f32_16x16x32_bf16(af[i], bf[j], acc[i][j], 0, 0, 0);
    }
    __syncthreads();
  }

  // C/D layout: col = lane&15, row = quad*4 + reg (verified m89/m91)
#pragma unroll
  for (int i = 0; i < 4; ++i) {
#pragma unroll
    for (int j = 0; j < 4; ++j) {
      int n = n0 + wc + j * 16 + l16;   // block-uniform branch (64-aligned base)
      if (n < C_) {
        int h = n >> 6, d = n & 63;
#pragma unroll
        for (int r = 0; r < 4; ++r) {
          int m = m0 + wr + i * 16 + quad * 4 + r;
          int b = m >> 11, t = m & (T_ - 1);
          Qo[(((size_t)b * H_ + h) * T_ + t) * HD_ + d] = f2bf(acc[i][j][r]);
        }
      } else {
        int nh = n - C_;
        int hh = nh >> 6, d = nh & 63;
#pragma unroll
        for (int r = 0; r < 4; ++r) {
          int m = m0 + wr + i * 16 + quad * 4 + r;
          int b = m >> 11, t = m & (T_ - 1);
          int bh = b * H_ + hh;
          size_t idx = (((((size_t)bh * 32 + (t >> 6)) * 4 + ((t >> 4) & 3)) * 2
                         + (d >> 5)) * 64 + ((d >> 3) & 3) * 16 + (t & 15)) * 8
                       + (d & 7);
          Kf[idx] = f2bf(acc[i][j][r]);
        }
      }
    }
  }
}

// ---------------------------------------------------------------------------
// Kernel 2: pack V (=x per head) into MFMA-B-fragment-linear layout Vf:
//   chunk (bh,kt,nb,c): lane (quad*16+l16) holds 16B =
//   V^T[d = nb*16+l16][key = kt*64 + c*32 + quad*8 .. +8]
// Stage the 64x64 x-tile in LDS (coalesced read), gather 8 u16, store 16B.
// ---------------------------------------------------------------------------
__global__ __launch_bounds__(256) void pack_vf(
    const float* __restrict__ X, u16* __restrict__ Vf)
{
  __shared__ u16 tr[64][65];     // [t][d], pitch 65: quads land on distinct banks
  const int kt = blockIdx.x, bh = blockIdx.y;
  const int b = bh >> 4, h = bh & 15;
  const int tid = threadIdx.x;
  {
    const int row = tid >> 2;
    const int c0  = (tid & 3) * 16;
    const float* xp = X + ((size_t)b * T_ + kt * 64 + row) * C_ + h * 64 + c0;
#pragma unroll
    for (int q = 0; q < 4; ++q) {
      float4 v = *(const float4*)(xp + q * 4);
      tr[row][c0 + q * 4 + 0] = f2bf(v.x);
      tr[row][c0 + q * 4 + 1] = f2bf(v.y);
      tr[row][c0 + q * 4 + 2] = f2bf(v.z);
      tr[row][c0 + q * 4 + 3] = f2bf(v.w);
    }
  }
  __syncthreads();
  const int w = tid >> 6, lane = tid & 63, quad = (lane >> 4), l16 = lane & 15;
  u16* outb = Vf + ((size_t)bh * 32 + kt) * 4096;
#pragma unroll
  for (int c = 0; c < 2; ++c) {   // wave w = nb
    u16 tmp[8];
#pragma unroll
    for (int j = 0; j < 8; ++j) tmp[j] = tr[c * 32 + quad * 8 + j][w * 16 + l16];
    *(bf16x8*)&outb[((w * 2 + c) * 64 + lane) * 8] = *(const bf16x8*)tmp;
  }
}

// ---------------------------------------------------------------------------
// Kernel 3a/3b: two-pass prefix scan (512 blocks per pass).
// ---------------------------------------------------------------------------
__global__ __launch_bounds__(256) void scanA(
    const float* __restrict__ X, float* __restrict__ SubP)
{
  const int ch = blockIdx.x, bh = blockIdx.y;
  const int b = bh >> 4, h = bh & 15;
  const int d = threadIdx.x & 63, s = threadIdx.x >> 6;
  const float* xp = X + (size_t)b * T_ * C_ + h * 64 + d;
  int t0 = ch * 128 + s * 32;
  float sum = 0.f;
#pragma unroll 8
  for (int i = 0; i < 32; ++i) sum += xp[(size_t)(t0 + i) * C_];
  SubP[((size_t)bh * 64 + ch * 4 + s) * 64 + d] = sum;
}

__global__ __launch_bounds__(256) void scanB(
    const float* __restrict__ X, const float* __restrict__ SubP,
    float* __restrict__ SP)
{
  const int ch = blockIdx.x, bh = blockIdx.y;
  const int b = bh >> 4, h = bh & 15;
  const int d = threadIdx.x & 63, s = threadIdx.x >> 6;
  const int gs = ch * 4 + s;
  const float* pp = SubP + (size_t)bh * 64 * 64 + d;
  float base = 0.f;
  for (int i = 0; i < gs; ++i) base += pp[(size_t)i * 64];
  const float* xp = X + (size_t)b * T_ * C_ + h * 64 + d;
  float* op = SP + (size_t)bh * T_ * HD_ + d;
  float sum = base;
  int t0 = gs * 32;
#pragma unroll 4
  for (int i = 0; i < 32; ++i) {
    int t = t0 + i;
    sum += xp[(size_t)t * C_];
    op[(size_t)t * HD_] = sum;
  }
}

// ---------------------------------------------------------------------------
// Kernel 4: barrier-free flash attention, fragment-linear K/V loads
// (every global load is lane*16B coalesced; per-tile working set 16KB -> L1).
// No running max (scores bounded ~2.5). Fused epilogue:
// out = beta*attn + alpha*x - gamma*SP/(t+1).
// ---------------------------------------------------------------------------
__global__ __launch_bounds__(256) void attn_kernel(
    const u16* __restrict__ Q, const u16* __restrict__ Kf, const u16* __restrict__ Vf,
    const float* __restrict__ SP, const float* __restrict__ X, float* __restrict__ out,
    const float* __restrict__ alphap, const float* __restrict__ betap,
    const float* __restrict__ gammap)
{
  __shared__ __align__(16) u16 pbuf[4][16][72];

  const int tid  = threadIdx.x;
  const int w    = tid >> 6;
  const int lane = tid & 63;
  const int quad = lane >> 4;
  const int l16  = lane & 15;
  const int qt = 31 - blockIdx.y;        // LPT: longest blocks dispatch first
  const int bh = blockIdx.x;
  const int b = bh >> 4, h = bh & 15;

  const u16* qb  = Q  + (size_t)bh * T_ * HD_;
  const u16* kfb = Kf + (size_t)bh * T_ * HD_;
  const u16* vfb = Vf + (size_t)bh * T_ * HD_;

  bf16x8 qfrag[2];
  {
    const u16* qp = qb + (size_t)(qt * 64 + w * 16 + l16) * HD_ + quad * 8;
    qfrag[0] = *(const bf16x8*)qp;
    qfrag[1] = *(const bf16x8*)(qp + 32);
  }

  f32x4 zero = {0.f, 0.f, 0.f, 0.f};
  f32x4 acc[4] = {zero, zero, zero, zero};
  float lsum[4] = {0.f, 0.f, 0.f, 0.f};
  const int myrow = w * 16 + quad * 4;

  for (int kt = 0; kt <= qt; ++kt) {
    const u16* kbase = kfb + (size_t)kt * 4096;
    const u16* vbase = vfb + (size_t)kt * 4096;
    bf16x8 kf[2][4], vf[2][4];
#pragma unroll
    for (int c = 0; c < 2; ++c)
#pragma unroll
      for (int nb = 0; nb < 4; ++nb)
        kf[c][nb] = *(const bf16x8*)&kbase[((nb * 2 + c) * 64 + lane) * 8];
#pragma unroll
    for (int c = 0; c < 2; ++c)
#pragma unroll
      for (int nb = 0; nb < 4; ++nb)
        vf[c][nb] = *(const bf16x8*)&vbase[((nb * 2 + c) * 64 + lane) * 8];

    f32x4 sfr[4] = {zero, zero, zero, zero};
#pragma unroll
    for (int c = 0; c < 2; ++c)
#pragma unroll
      for (int nb = 0; nb < 4; ++nb)
        sfr[nb] = __builtin_amdgcn_mfma_f32_16x16x32_bf16(qfrag[c], kf[c][nb], sfr[nb], 0, 0, 0);

    const bool diag = (kt == qt);
#pragma unroll
    for (int nb = 0; nb < 4; ++nb) {
#pragma unroll
      for (int r = 0; r < 4; ++r) {
        float p = __expf(sfr[nb][r] * 0.125f);
        if (diag && (nb * 16 + l16 > myrow + r)) p = 0.f;
        lsum[r] += p;
        pbuf[w][quad * 4 + r][nb * 16 + l16] = f2bf(p);
      }
    }

#pragma unroll
    for (int c = 0; c < 2; ++c) {
      bf16x8 pf = *(const bf16x8*)&pbuf[w][l16][c * 32 + quad * 8];
#pragma unroll
      for (int nb = 0; nb < 4; ++nb)
        acc[nb] = __builtin_amdgcn_mfma_f32_16x16x32_bf16(pf, vf[c][nb], acc[nb], 0, 0, 0);
    }
  }

#pragma unroll
  for (int r = 0; r < 4; ++r) {
    float s = lsum[r];
    s += __shfl_xor(s, 1);
    s += __shfl_xor(s, 2);
    s += __shfl_xor(s, 4);
    s += __shfl_xor(s, 8);
    lsum[r] = s;
  }

  const float alpha = *alphap, beta = *betap, gamma = *gammap;
#pragma unroll
  for (int nb = 0; nb < 4; ++nb) {
#pragma unroll
    for (int r = 0; r < 4; ++r) {
      int t = qt * 64 + myrow + r;
      int d = nb * 16 + l16;
      float att = acc[nb][r] / lsum[r];
      float pref = SP[((size_t)bh * T_ + t) * HD_ + d];
      size_t xi = ((size_t)b * T_ + t) * C_ + h * 64 + d;
      out[xi] = beta * att + alpha * X[xi] - gamma * pref / (float)(t + 1);
    }
  }
}

// ---------------------------------------------------------------------------
extern "C" void kernel_launch(void* const* d_in, const int* in_sizes, int n_in,
                              void* d_out, int out_size, void* d_ws, size_t ws_size,
                              hipStream_t stream) {
  const float* x      = (const float*)d_in[0];
  const float* W_attn = (const float*)d_in[1];
  const float* alphap = (const float*)d_in[2];
  const float* betap  = (const float*)d_in[3];
  const float* gammap = (const float*)d_in[4];
  float* out = (float*)d_out;

  // ws: Qb@0(8M) Kf@8(8M) Vf@16(8M) SP@24(16M) SubP@40(.5M) Xb@41(8M) Wb@49(4M)
  char* ws = (char*)d_ws;
  u16*   Qb   = (u16*)(ws);
  u16*   Kfb  = (u16*)(ws + (8ull  << 20));
  u16*   Vfb  = (u16*)(ws + (16ull << 20));
  float* SPb  = (float*)(ws + (24ull << 20));
  float* SubP = (float*)(ws + (40ull << 20));
  u16*   Xb   = (u16*)(ws + (41ull << 20));
  u16*   Wb   = (u16*)(ws + (49ull << 20));

  convert_bf16<<<(NX4 + NW4) / 256, 256, 0, stream>>>(x, W_attn, Xb, Wb);
  gemm_qk<<<dim3(16, 32), 256, 0, stream>>>(Xb, Wb, Qb, Kfb);
  pack_vf<<<dim3(32, 32), 256, 0, stream>>>(x, Vfb);
  scanA<<<dim3(16, 32), 256, 0, stream>>>(x, SubP);
  scanB<<<dim3(16, 32), 256, 0, stream>>>(x, SubP, SPb);
  attn_kernel<<<dim3(32, 32), 256, 0, stream>>>(Qb, Kfb, Vfb, SPb, x, out,
                                                alphap, betap, gammap);
}